// Round 5
// baseline (428.666 us; speedup 1.0000x reference)
//
#include <hip/hip_runtime.h>

#define D 512
#define NNODES 1365
#define OUT_STRIDE (NNODES * D)   // 698880 floats per batch row

typedef __attribute__((ext_vector_type(4))) float f32x4;
typedef __attribute__((ext_vector_type(8))) short bf16x8;

union U4 { uint4 q; unsigned u[4]; bf16x8 v; };

__device__ inline unsigned cvt_pk_bf16(float s0, float s1) {
    unsigned r;
    asm volatile("v_cvt_pk_bf16_f32 %0, %1, %2" : "=v"(r) : "v"(s0), "v"(s1));
    return r;
}

__device__ inline void gld_lds16(const void* g, void* l) {
    __builtin_amdgcn_global_load_lds(
        (const __attribute__((address_space(1))) unsigned*)g,
        (__attribute__((address_space(3))) unsigned*)l, 16, 0, 0);
}

// Barrier-free per-wave streaming, LINEAR chunks. Chunk = 4 complete W-rows
// (8 KB contiguous). MFMA 16x16x32 with only 4 valid N-rows (lanes c0>=4
// compute garbage, never stored) -- 4x MFMA waste, irrelevant at 25x
// memory-bound. LDS 16B-unit permutation u = ks*32 + (row>>1)*8 +
// (row&1)*4 + m4 makes B-frag ds_read_b128 exactly 2-way (free); applied by
// pre-permuting the per-lane GLOBAL source, LDS dest linear. Counted vmcnt
// per unrolled iter never waits on the next chunk.
template<int NC, bool RELU>
__global__ __launch_bounds__(256, 2)
void node_kernel(const float* __restrict__ W,
                 const float* __restrict__ bias,
                 const float* __restrict__ src_base,   // inputs (lvl0) or out
                 float* __restrict__ out,
                 int node_start, int bpn, int src_stride)
{
    __shared__ float Wt[4][2][2048];   // 4 waves x 2 bufs x 8 KB = 64 KB

    const int tid  = threadIdx.x;
    const int w    = tid >> 6;
    const int lane = tid & 63;
    const int m4   = lane >> 4;
    const int c0   = lane & 15;

    const int node  = node_start + blockIdx.x / bpn;
    const int nbase = (blockIdx.x % bpn) * (16 * NC);
    const float* Wn = W + (size_t)node * (D * D);

    // DMA source decode for LDS unit u = i*64 + lane:
    //   m4u = lane&3, row = ((lane>>2)&1) + 2*((lane>>3)&1),
    //   t = (lane>>4)&1, ks = i*2 + (lane>>5)
    //   global byte = row*2048 + (ks*8 + m4u*2 + t)*16 = loff + i*256
    const int drow = ((lane >> 2) & 1) + 2 * ((lane >> 3) & 1);
    const int loff = drow * 2048 +
        ((lane >> 5) * 8 + (lane & 3) * 2 + ((lane >> 4) & 1)) * 16;

    auto issue_chunk = [&](int c) {
        const char* gsrc = (const char*)Wn +
            (size_t)(nbase + (c * 4 + w) * 4) * 2048 + loff;
        char* ldst = (char*)&Wt[w][c & 1][0];
        #pragma unroll
        for (int i = 0; i < 8; ++i)
            gld_lds16(gsrc + i * 256, ldst + i * 1024);
    };

    // ---- prologue: bias preload (oldest vmem, drained by first wait) ----
    float bf[NC];
    #pragma unroll
    for (int c = 0; c < NC; ++c) {
        bf[c] = bias[(size_t)node * D + nbase + (c * 4 + w) * 4 + (c0 & 3)];
        asm volatile("" :: "v"(bf[c]));
    }

    // ---- A-frags: pa row c0 (batch), full K, bf16 hi/lo in registers ----
    const float* arow = (RELU ? src_base + (size_t)((node - 1) >> 2) * D
                              : src_base) + (size_t)c0 * src_stride;
    bf16x8 aH[16], aL[16];
    #pragma unroll
    for (int j = 0; j < 16; ++j) {
        const float* p = arow + j * 32 + m4 * 8;
        float4 x0 = *(const float4*)p;
        float4 x1 = *(const float4*)(p + 4);
        float xs[8] = {x0.x,x0.y,x0.z,x0.w,x1.x,x1.y,x1.z,x1.w};
        U4 h, l;
        #pragma unroll
        for (int k = 0; k < 4; ++k) {
            unsigned hh = cvt_pk_bf16(xs[2*k], xs[2*k+1]);
            float f0 = __uint_as_float(hh << 16);
            float f1 = __uint_as_float(hh & 0xFFFF0000u);
            l.u[k] = cvt_pk_bf16(xs[2*k] - f0, xs[2*k+1] - f1);
            h.u[k] = hh;
        }
        aH[j] = h.v; aL[j] = l.v;
    }

    issue_chunk(0);
    if (NC > 1) issue_chunk(1);

    // B-frag read offset: unit u0 = ks*32 + ((c0>>1)&1)*8 + (c0&1)*4 + m4
    const int laneoff = ((c0 >> 1) & 1) * 128 + (c0 & 1) * 64 + m4 * 16;

    #pragma unroll
    for (int c = 0; c < NC; ++c) {
        // wait for chunk c; threshold = count of vmem ops younger than c's
        // loads (never waits on chunk c+1): c=0 -> 8; c=1 -> 12 (+store0);
        // 2<=c<=NC-2 -> 16 (+2 stores); last -> 0 (tail drain).
        if      (c == NC - 1) asm volatile("s_waitcnt vmcnt(0)"  ::: "memory");
        else if (c == 0)      asm volatile("s_waitcnt vmcnt(8)"  ::: "memory");
        else if (c == 1)      asm volatile("s_waitcnt vmcnt(12)" ::: "memory");
        else                  asm volatile("s_waitcnt vmcnt(16)" ::: "memory");

        const char* tb = (const char*)&Wt[w][c & 1][0];
        f32x4 acc = {0.f, 0.f, 0.f, 0.f};
        #pragma unroll
        for (int ks = 0; ks < 16; ++ks) {
            float4 b0 = *(const float4*)(tb + ks * 512 + laneoff);
            float4 b1 = *(const float4*)(tb + ks * 512 + laneoff + 256);
            U4 bH, bL;
            float xs[8] = {b0.x,b0.y,b0.z,b0.w,b1.x,b1.y,b1.z,b1.w};
            #pragma unroll
            for (int k = 0; k < 4; ++k) {
                unsigned hh = cvt_pk_bf16(xs[2*k], xs[2*k+1]);
                float f0 = __uint_as_float(hh << 16);
                float f1 = __uint_as_float(hh & 0xFFFF0000u);
                bL.u[k] = cvt_pk_bf16(xs[2*k] - f0, xs[2*k+1] - f1);
                bH.u[k] = hh;
            }
            acc = __builtin_amdgcn_mfma_f32_16x16x32_bf16(aH[ks], bH.v, acc, 0,0,0);
            acc = __builtin_amdgcn_mfma_f32_16x16x32_bf16(aL[ks], bH.v, acc, 0,0,0);
            acc = __builtin_amdgcn_mfma_f32_16x16x32_bf16(aH[ks], bL.v, acc, 0,0,0);
        }

        if (c + 2 < NC) issue_chunk(c + 2);

        // epilogue: only lanes c0<4 hold valid C columns (W-rows r0..r0+3)
        if (c0 < 4) {
            const int wcol = node * D + nbase + (c * 4 + w) * 4 + c0;
            const float bv = bf[c];
            #pragma unroll
            for (int i = 0; i < 4; ++i) {
                float v = acc[i] + bv;
                if (RELU) v = fmaxf(v, 0.f);
                out[(size_t)(m4 * 4 + i) * OUT_STRIDE + wcol] = v;
            }
        }
    }
}

extern "C" void kernel_launch(void* const* d_in, const int* in_sizes, int n_in,
                              void* d_out, int out_size, void* d_ws, size_t ws_size,
                              hipStream_t stream) {
    const float* inputs = (const float*)d_in[0];   // (16, 512)
    const float* W      = (const float*)d_in[1];   // (1365, 512, 512)
    const float* bias   = (const float*)d_in[2];   // (1365, 512)
    float* out          = (float*)d_out;           // (16, 1365*512)

    // <NC, RELU> <<<nodes*bpn>>> (node_start, bpn, src_stride); block covers
    // 16*NC rows, bpn = 32/NC blocks per node.
    node_kernel<1, false><<<  32, 256, 0, stream>>>(W, bias, inputs, out,   0, 32, D);
    node_kernel<1, true ><<< 128, 256, 0, stream>>>(W, bias, out,    out,   1, 32, OUT_STRIDE);
    node_kernel<2, true ><<< 256, 256, 0, stream>>>(W, bias, out,    out,   5, 16, OUT_STRIDE);
    node_kernel<4, true ><<< 512, 256, 0, stream>>>(W, bias, out,    out,  21,  8, OUT_STRIDE);
    node_kernel<8, true ><<<1024, 256, 0, stream>>>(W, bias, out,    out,  85,  4, OUT_STRIDE);
    node_kernel<8, true ><<<4096, 256, 0, stream>>>(W, bias, out,    out, 341,  4, OUT_STRIDE);
}

// Round 6
// 346.265 us; speedup vs baseline: 1.2380x; 1.2380x over previous
//
#include <hip/hip_runtime.h>

#define D 512
#define NNODES 1365
#define OUT_STRIDE (NNODES * D)   // 698880 floats per batch row

typedef __attribute__((ext_vector_type(4))) float f32x4;
typedef __attribute__((ext_vector_type(8))) short bf16x8;

union U4 { uint4 q; unsigned u[4]; bf16x8 v; };

__device__ inline unsigned cvt_pk_bf16(float s0, float s1) {
    unsigned r;
    asm volatile("v_cvt_pk_bf16_f32 %0, %1, %2" : "=v"(r) : "v"(s0), "v"(s1));
    return r;
}

__device__ inline void gld_lds16(const void* g, void* l) {
    __builtin_amdgcn_global_load_lds(
        (const __attribute__((address_space(1))) unsigned*)g,
        (__attribute__((address_space(3))) unsigned*)l, 16, 0, 0);
}

// Per-wave streaming GEMM, COMPACT dynamic group loop (I-cache friendly).
// Group = 64 rows (wave w owns rows (g*4+w)*16..+16), processed as 4 chunks
// of 8 KB (16 rows x 512 B K-quarter), double-buffered per wave. A operand
// (pa) as bf16 hi/lo frags in registers (static indexing). Split-bf16:
// AhBh + AlBh + AhBl. Uniform counted vmcnt(8); vmcnt(0) only at tail.
template<bool RELU>
__global__ __launch_bounds__(256, 2)
void node_kernel(const float* __restrict__ W,
                 const float* __restrict__ bias,
                 const float* __restrict__ src_base,   // inputs (lvl0) or out
                 float* __restrict__ out,
                 int node_start, int bpn, int ngroups, int src_stride)
{
    __shared__ float Wt[4][2][2048];   // 4 waves x 2 bufs x 8 KB = 64 KB
    __shared__ float bias_lds[512];    // up to 8 groups x 64 rows

    const int tid  = threadIdx.x;
    const int w    = tid >> 6;
    const int lane = tid & 63;
    const int m4   = lane >> 4;
    const int c0   = lane & 15;

    const int node  = node_start + blockIdx.x / bpn;
    const int nbase = (blockIdx.x % bpn) * (64 * ngroups);
    const char* Wn  = (const char*)(W + (size_t)node * (D * D));

    // ---- stage bias slice into LDS ----
    for (int t = tid; t < 64 * ngroups; t += 256)
        bias_lds[t] = bias[(size_t)node * D + nbase + t];

    // ---- A-frags: pa row c0 (batch), full K, bf16 hi/lo in registers ----
    const float* arow = (RELU ? src_base + (size_t)((node - 1) >> 2) * D
                              : src_base) + (size_t)c0 * src_stride;
    bf16x8 aH[16], aL[16];
    #pragma unroll
    for (int j = 0; j < 16; ++j) {
        const float* p = arow + j * 32 + m4 * 8;
        float4 x0 = *(const float4*)p;
        float4 x1 = *(const float4*)(p + 4);
        float xs[8] = {x0.x,x0.y,x0.z,x0.w,x1.x,x1.y,x1.z,x1.w};
        U4 h, l;
        #pragma unroll
        for (int k = 0; k < 4; ++k) {
            unsigned hh = cvt_pk_bf16(xs[2*k], xs[2*k+1]);
            float f0 = __uint_as_float(hh << 16);
            float f1 = __uint_as_float(hh & 0xFFFF0000u);
            l.u[k] = cvt_pk_bf16(xs[2*k] - f0, xs[2*k+1] - f1);
            h.u[k] = hh;
        }
        aH[j] = h.v; aL[j] = l.v;
    }
    __syncthreads();   // bias visible to all waves; drains prologue vmem

    // per-lane DMA source offsets for the 8 insts of an 8 KB chunk:
    // inst i covers rows i*2+rr (rr=lane>>5), 32 lanes x 16 B per row,
    // XOR-swizzled within the row's 512 B K-slice.
    int loffs[8];
    const int rr  = lane >> 5;
    const int off = (lane & 31) * 16;
    #pragma unroll
    for (int i = 0; i < 8; ++i) {
        const int r = i * 2 + rr;
        loffs[i] = r * 2048 + (off ^ ((r & 7) << 4));
    }

    auto issue = [&](const char* gsrc, int buf) {
        char* ldst = (char*)&Wt[w][buf][0];
        #pragma unroll
        for (int i = 0; i < 8; ++i)
            gld_lds16(gsrc + loffs[i], ldst + i * 1024);
    };

    // B-frag LDS read offsets (swizzle folded; b1 needs XOR before add!)
    const int rsw = (c0 & 7) << 4;
    const int po0 = c0 * 512 + ((m4 * 32)      ^ rsw);
    const int po1 = c0 * 512 + ((m4 * 32 + 16) ^ rsw);

    const size_t GRP = (size_t)64 * 2048;             // group stride: 128 KB
    const char* gcur = Wn + (size_t)(nbase + w * 16) * 2048;
    issue(gcur,       0);                             // chunk (0,0)
    issue(gcur + 512, 1);                             // chunk (0,1)

    float* optr = out + (size_t)node * D + nbase + w * 16 + c0;
    const float* blds = &bias_lds[w * 16 + c0];

    // one K-quarter of MFMA work from buffer Q&1
    auto compute_q = [&](auto qc, f32x4& acc) {
        constexpr int Q = decltype(qc)::value;
        const char* tb = (const char*)&Wt[w][Q & 1][0];
        #pragma unroll
        for (int ks = 0; ks < 4; ++ks) {
            float4 b0 = *(const float4*)(tb + po0 + ks * 128);
            float4 b1 = *(const float4*)(tb + po1 + ks * 128);
            U4 bH, bL;
            float xs[8] = {b0.x,b0.y,b0.z,b0.w,b1.x,b1.y,b1.z,b1.w};
            #pragma unroll
            for (int k = 0; k < 4; ++k) {
                unsigned hh = cvt_pk_bf16(xs[2*k], xs[2*k+1]);
                float f0 = __uint_as_float(hh << 16);
                float f1 = __uint_as_float(hh & 0xFFFF0000u);
                bL.u[k] = cvt_pk_bf16(xs[2*k] - f0, xs[2*k+1] - f1);
                bH.u[k] = hh;
            }
            acc = __builtin_amdgcn_mfma_f32_16x16x32_bf16(aH[Q*4+ks], bH.v, acc, 0,0,0);
            acc = __builtin_amdgcn_mfma_f32_16x16x32_bf16(aL[Q*4+ks], bH.v, acc, 0,0,0);
            acc = __builtin_amdgcn_mfma_f32_16x16x32_bf16(aH[Q*4+ks], bL.v, acc, 0,0,0);
        }
    };

    #pragma clang loop unroll(disable)
    for (int g = 0; g < ngroups; ++g) {
        const bool last = (g == ngroups - 1);
        const char* gnext = gcur + GRP;
        f32x4 acc = {0.f, 0.f, 0.f, 0.f};

        // q0: read buf0 (g,0); then prefetch (g,2) -> buf0
        asm volatile("s_waitcnt vmcnt(8)" ::: "memory");
        compute_q(std::integral_constant<int,0>{}, acc);
        issue(gcur + 1024, 0);
        // q1: read buf1 (g,1); prefetch (g,3) -> buf1
        asm volatile("s_waitcnt vmcnt(8)" ::: "memory");
        compute_q(std::integral_constant<int,1>{}, acc);
        issue(gcur + 1536, 1);
        // q2: read buf0 (g,2); prefetch (g+1,0) -> buf0
        asm volatile("s_waitcnt vmcnt(8)" ::: "memory");
        compute_q(std::integral_constant<int,2>{}, acc);
        if (!last) issue(gnext, 0);
        // q3: read buf1 (g,3); epilogue; prefetch (g+1,1) -> buf1
        if (last) asm volatile("s_waitcnt vmcnt(0)" ::: "memory");
        else      asm volatile("s_waitcnt vmcnt(8)" ::: "memory");
        compute_q(std::integral_constant<int,3>{}, acc);

        const float bv = *blds;
        #pragma unroll
        for (int i = 0; i < 4; ++i) {
            float v = acc[i] + bv;
            if (RELU) v = fmaxf(v, 0.f);
            optr[(size_t)(m4 * 4 + i) * OUT_STRIDE] = v;
        }
        if (!last) issue(gnext + 512, 1);

        gcur = gnext; optr += 64; blds += 64;
    }
}

extern "C" void kernel_launch(void* const* d_in, const int* in_sizes, int n_in,
                              void* d_out, int out_size, void* d_ws, size_t ws_size,
                              hipStream_t stream) {
    const float* inputs = (const float*)d_in[0];   // (16, 512)
    const float* W      = (const float*)d_in[1];   // (1365, 512, 512)
    const float* bias   = (const float*)d_in[2];   // (1365, 512)
    float* out          = (float*)d_out;           // (16, 1365*512)

    // <RELU> <<<nodes*bpn>>> (node_start, bpn, ngroups, src_stride)
    // block covers 64*ngroups rows of one node.
    node_kernel<false><<<   8, 256, 0, stream>>>(W, bias, inputs, out,   0, 8, 1, D);
    node_kernel<true ><<<  32, 256, 0, stream>>>(W, bias, out,    out,   1, 8, 1, OUT_STRIDE);
    node_kernel<true ><<< 128, 256, 0, stream>>>(W, bias, out,    out,   5, 8, 1, OUT_STRIDE);
    node_kernel<true ><<< 512, 256, 0, stream>>>(W, bias, out,    out,  21, 8, 1, OUT_STRIDE);
    node_kernel<true ><<< 512, 256, 0, stream>>>(W, bias, out,    out,  85, 2, 4, OUT_STRIDE);
    node_kernel<true ><<<1024, 256, 0, stream>>>(W, bias, out,    out, 341, 1, 8, OUT_STRIDE);
}